// Round 2
// baseline (83.749 us; speedup 1.0000x reference)
//
#include <hip/hip_runtime.h>
#include <math.h>

// Problem constants (fixed by setup_inputs): S=64, IN=OUT=128, D=32, HID=128.
// Key identity: j % IN == j % OUT == o for j = i*OUT + o, so the generated
// weight tensor is constant along i:  out[s,o] = rowsum(x[s,:]) * g(s,o).
#define NS   64
#define NIN  128
#define NOUT 128
#define HID  128
#define DM   32   // d_model

#define LN10000 9.210340371976184f

// ---------------- kernel 1: precompute base tables ----------------
// base_w[o,h] = b1[h] + sum_k pe(o)[k] * (w1[k,h] + w1[32+k,h])
// base_b[o,h] = bb1[h] + sum_k pe(o)[k] * bw1[k,h]
__global__ void vnn_base_kernel(const float* __restrict__ w1,
                                const float* __restrict__ b1,
                                const float* __restrict__ bw1,
                                const float* __restrict__ bb1,
                                float* __restrict__ base_w,
                                float* __restrict__ base_b) {
    const int o = blockIdx.x;    // 0..127 (position)
    const int h = threadIdx.x;   // 0..127 (hidden unit)
    __shared__ float pe[DM];
    if (h < DM / 2) {
        // div[k] = exp(2k * -ln(10000)/32) = exp(-k*ln(10000)/16)
        float div = expf((float)h * (-LN10000 / 16.0f));
        float ang = (float)o * div;
        pe[2 * h]     = sinf(ang);
        pe[2 * h + 1] = cosf(ang);
    }
    __syncthreads();

    float aw = b1[h];
    float ab = bb1[h];
#pragma unroll
    for (int k = 0; k < DM; ++k) {
        float p = pe[k];
        aw += p * (w1[k * HID + h] + w1[(DM + k) * HID + h]);  // coalesced over h
        ab += p * bw1[k * HID + h];
    }
    base_w[o * HID + h] = aw;
    base_b[o * HID + h] = ab;
}

// ---------------- kernel 2: per-(s,o) output ----------------
__global__ void vnn_out_kernel(const float* __restrict__ x,
                               const float* __restrict__ w1,
                               const float* __restrict__ w2,
                               const float* __restrict__ b2,
                               const float* __restrict__ bw1,
                               const float* __restrict__ bw2,
                               const float* __restrict__ bb2,
                               const float* __restrict__ base_w,
                               const float* __restrict__ base_b,
                               float* __restrict__ out) {
    const int s = blockIdx.x;    // 0..63
    const int o = threadIdx.x;   // 0..127

    __shared__ float s_w164[HID];   // w1 row 64 (the x coefficient)
    __shared__ float s_w2[HID];
    __shared__ float s_bw32[HID];   // bw1 row 32 (the out coefficient)
    __shared__ float s_bw2[HID];
    __shared__ float wsum[2];

    s_w164[o] = w1[(2 * DM) * HID + o];
    s_w2[o]   = w2[o];
    s_bw32[o] = bw1[DM * HID + o];
    s_bw2[o]  = bw2[o];

    const float xv = x[s * NIN + o];

    // rowsum(x[s,:]) across the 128 threads (2 waves)
    float v = xv;
#pragma unroll
    for (int off = 32; off > 0; off >>= 1) v += __shfl_xor(v, off, 64);
    if ((o & 63) == 0) wsum[o >> 6] = v;
    __syncthreads();
    const float Sx = wsum[0] + wsum[1];

    // weight-MLP scalar: g = b2 + sum_h relu(base_w[o,h] + xv*w1[64,h]) * w2[h]
    const float4* bw4 = reinterpret_cast<const float4*>(base_w + o * HID);
    float g = 0.0f;
#pragma unroll 8
    for (int h4 = 0; h4 < HID / 4; ++h4) {
        float4 b = bw4[h4];
        int h = h4 * 4;
        g += fmaxf(b.x + xv * s_w164[h + 0], 0.0f) * s_w2[h + 0];
        g += fmaxf(b.y + xv * s_w164[h + 1], 0.0f) * s_w2[h + 1];
        g += fmaxf(b.z + xv * s_w164[h + 2], 0.0f) * s_w2[h + 2];
        g += fmaxf(b.w + xv * s_w164[h + 3], 0.0f) * s_w2[h + 3];
    }
    g += b2[0];
    const float out0 = Sx * g;

    // bias-MLP scalar: bias = bb2 + sum_h relu(base_b[o,h] + out0*bw1[32,h]) * bw2[h]
    const float4* bb4 = reinterpret_cast<const float4*>(base_b + o * HID);
    float bias = 0.0f;
#pragma unroll 8
    for (int h4 = 0; h4 < HID / 4; ++h4) {
        float4 b = bb4[h4];
        int h = h4 * 4;
        bias += fmaxf(b.x + out0 * s_bw32[h + 0], 0.0f) * s_bw2[h + 0];
        bias += fmaxf(b.y + out0 * s_bw32[h + 1], 0.0f) * s_bw2[h + 1];
        bias += fmaxf(b.z + out0 * s_bw32[h + 2], 0.0f) * s_bw2[h + 2];
        bias += fmaxf(b.w + out0 * s_bw32[h + 3], 0.0f) * s_bw2[h + 3];
    }
    bias += bb2[0];

    out[s * NOUT + o] = out0 + bias;
}

extern "C" void kernel_launch(void* const* d_in, const int* in_sizes, int n_in,
                              void* d_out, int out_size, void* d_ws, size_t ws_size,
                              hipStream_t stream) {
    const float* x   = (const float*)d_in[0];
    const float* w1  = (const float*)d_in[1];
    const float* b1  = (const float*)d_in[2];
    const float* w2  = (const float*)d_in[3];
    const float* b2  = (const float*)d_in[4];
    const float* bw1 = (const float*)d_in[5];
    const float* bb1 = (const float*)d_in[6];
    const float* bw2 = (const float*)d_in[7];
    const float* bb2 = (const float*)d_in[8];
    float* out = (float*)d_out;

    float* base_w = (float*)d_ws;                       // 128*128 f32 = 64 KB
    float* base_b = base_w + NOUT * HID;                // 128*128 f32 = 64 KB

    vnn_base_kernel<<<NOUT, HID, 0, stream>>>(w1, b1, bw1, bb1, base_w, base_b);
    vnn_out_kernel<<<NS, HID, 0, stream>>>(x, w1, w2, b2, bw1, bw2, bb2,
                                           base_w, base_b, out);
}